// Round 9
// baseline (413.572 us; speedup 1.0000x reference)
//
#include <hip/hip_runtime.h>

namespace {
constexpr int NWIN = 512;
constexpr int M    = 32;
constexpr int H    = 8;
constexpr int C    = 16;
constexpr int NSIG = 3;
constexpr int HC   = H * C;   // 128 floats per voxel row
constexpr int HB   = 4;       // heads per block (window split across 2 blocks)
constexpr int HBC  = HB * C;  // 64 floats of k/v staged per voxel
}

__device__ __forceinline__ float dot4(const float4& a, const float4& b) {
  return a.x * b.x + a.y * b.y + a.z * b.z + a.w * b.w;
}
__device__ __forceinline__ const float4* f4p(const float* p) {
  return reinterpret_cast<const float4*>(p);
}

// Two blocks per window (4 heads each), 256 threads:
//   t -> hl = t>>6 (local head, one per wave), ch = (t>>5)&1 (channel half),
//        i = t&31 (query voxel). h = hb + hl; channels [ch*8, ch*8+8).
// Each thread dots over its 8 channels; one __shfl_xor(acc,32) per j combines
// the halves (both halves then hold identical lg[] -> thread-local softmax).
// Grid 1024 -> 4 blocks/CU (VGPR<=128, LDS 28.4KB) = 16 waves/CU, 2x the
// round-4 baseline which profiled latency-bound (VALUBusy 9.4%, occ 23%).
__global__ __launch_bounds__(256, 4)
void win_attn(const float* __restrict__ qf, const float* __restrict__ kf,
              const float* __restrict__ vf, const float* __restrict__ qt,
              const float* __restrict__ kt, const float* __restrict__ vt,
              const int* __restrict__ toff, const int* __restrict__ widx,
              const int* __restrict__ tidx, float* __restrict__ out)
{
  const int w  = blockIdx.x >> 1;
  const int hb = (blockIdx.x & 1) * HB;   // head base for this block
  const int t  = threadIdx.x;
  const int hl = t >> 6;                  // local head 0..3 (wave id)
  const int ch = (t >> 5) & 1;            // channel half 0..1
  const int i  = t & 31;
  const int h  = hb + hl;                 // global head 0..7
  const int cb = ch * 8;                  // channel base within head

  __shared__ float k_lds[M][HBC];          // 8 KB (4-head slice)
  __shared__ float v_lds[M][HBC];          // 8 KB
  __shared__ int   tid_lds[M * NSIG * M];  // 12 KB, [(j*3+s)*32 + i]
  __shared__ int   vox_lds[M];
  __shared__ int   off_lds[NSIG];

  if (t < M)    vox_lds[t] = widx[w * M + t];
  if (t < NSIG) off_lds[t] = toff[t];
  __syncthreads();

  // Stage the block's 4-head slice of k,v: 512 float4 per table.
  #pragma unroll
  for (int r = 0; r < 2; ++r) {
    const int flat = t + 256 * r;        // [0,512)
    const int j    = flat >> 4;          // voxel 0..31
    const int f4i  = (flat & 15) * 4;    // float index within 64-float slice
    const int goff = vox_lds[j] * HC + hb * C + f4i;
    *reinterpret_cast<float4*>(&k_lds[j][f4i]) = *f4p(kf + goff);
    *reinterpret_cast<float4*>(&v_lds[j][f4i]) = *f4p(vf + goff);
  }
  // Stage table_idx (global layout [i][j][s]) transposed to [(j*3+s)*32+i].
  #pragma unroll
  for (int r = 0; r < 12; ++r) {
    const int g   = t + 256 * r;         // [0,3072)
    const int ii  = g / 96;
    const int rem = g - ii * 96;
    const int jj  = rem / 3;
    const int ss  = rem - jj * 3;
    tid_lds[(jj * NSIG + ss) * M + ii] = tidx[w * (M * M * NSIG) + g];
  }

  // q half-slice for (i,h,ch): 8 floats in registers.
  const int vox_i = vox_lds[i];
  const float* qrow = qf + vox_i * HC + h * C + cb;
  const float4 q0 = f4p(qrow)[0], q1 = f4p(qrow)[1];
  const int offs[NSIG] = { off_lds[0], off_lds[1], off_lds[2] };
  __syncthreads();

  // ---- Phase 1: logits (fully unrolled j so lg[] stays in registers) ----
  float lg[M];
  #pragma unroll
  for (int j = 0; j < M; ++j) {
    const float* krow = &k_lds[j][hl * C + cb];
    const float4 k0 = f4p(krow)[0], k1 = f4p(krow)[1];
    float acc = dot4(q0, k0) + dot4(q1, k1);
    #pragma unroll
    for (int s = 0; s < NSIG; ++s) {
      const int row = offs[s] + tid_lds[(j * NSIG + s) * M + i];
      const float* tqr = qt + row * HC + h * C + cb;
      acc += dot4(q0, f4p(tqr)[0]) + dot4(q1, f4p(tqr)[1]);
      const float* tkr = kt + row * HC + h * C + cb;
      acc += dot4(k0, f4p(tkr)[0]) + dot4(k1, f4p(tkr)[1]);
    }
    acc += __shfl_xor(acc, 32);   // combine the two channel halves
    lg[j] = acc;
  }

  // ---- Phase 2: max-stabilized softmax, thread-local in registers ----
  float m = lg[0];
  #pragma unroll
  for (int j = 1; j < M; ++j) m = fmaxf(m, lg[j]);
  float ssum = 0.f;
  #pragma unroll
  for (int j = 0; j < M; ++j) { lg[j] = expf(lg[j] - m); ssum += lg[j]; }

  // ---- Phase 3: PV + table-V over this thread's 8 channels ----
  float oacc[8];
  #pragma unroll
  for (int c = 0; c < 8; ++c) oacc[c] = 0.f;
  #pragma unroll
  for (int j = 0; j < M; ++j) {
    const float e = lg[j];
    const float* vrow = &v_lds[j][hl * C + cb];
    #pragma unroll
    for (int c4 = 0; c4 < 2; ++c4) {
      const float4 vv = f4p(vrow)[c4];
      oacc[4 * c4 + 0] += e * vv.x;
      oacc[4 * c4 + 1] += e * vv.y;
      oacc[4 * c4 + 2] += e * vv.z;
      oacc[4 * c4 + 3] += e * vv.w;
    }
    #pragma unroll
    for (int s = 0; s < NSIG; ++s) {
      const int row = offs[s] + tid_lds[(j * NSIG + s) * M + i];
      const float* tvr = vt + row * HC + h * C + cb;
      #pragma unroll
      for (int c4 = 0; c4 < 2; ++c4) {
        const float4 tv = f4p(tvr)[c4];
        oacc[4 * c4 + 0] += e * tv.x;
        oacc[4 * c4 + 1] += e * tv.y;
        oacc[4 * c4 + 2] += e * tv.z;
        oacc[4 * c4 + 3] += e * tv.w;
      }
    }
  }

  const float inv = 1.0f / ssum;
  float* orow = out + vox_i * HC + h * C + cb;
  #pragma unroll
  for (int c4 = 0; c4 < 2; ++c4) {
    float4 o;
    o.x = oacc[4 * c4 + 0] * inv;
    o.y = oacc[4 * c4 + 1] * inv;
    o.z = oacc[4 * c4 + 2] * inv;
    o.w = oacc[4 * c4 + 3] * inv;
    *reinterpret_cast<float4*>(orow + 4 * c4) = o;
  }
}

extern "C" void kernel_launch(void* const* d_in, const int* in_sizes, int n_in,
                              void* d_out, int out_size, void* d_ws, size_t ws_size,
                              hipStream_t stream) {
  (void)in_sizes; (void)n_in; (void)d_ws; (void)ws_size; (void)out_size;
  const float* qf  = (const float*)d_in[0];
  const float* kf  = (const float*)d_in[1];
  const float* vf  = (const float*)d_in[2];
  const float* qt  = (const float*)d_in[3];
  const float* kt  = (const float*)d_in[4];
  const float* vt  = (const float*)d_in[5];
  const int*  toff = (const int*)d_in[6];
  const int*  widx = (const int*)d_in[7];
  const int*  tidx = (const int*)d_in[8];
  float* out = (float*)d_out;
  win_attn<<<NWIN * 2, 256, 0, stream>>>(qf, kf, vf, qt, kt, vt, toff, widx, tidx, out);
}

// Round 13
// 351.702 us; speedup vs baseline: 1.1759x; 1.1759x over previous
//
#include <hip/hip_runtime.h>

namespace {
constexpr int NWIN = 512;
constexpr int M    = 32;
constexpr int H    = 8;
constexpr int C    = 16;
constexpr int NSIG = 3;
constexpr int HC   = H * C;   // 128 floats per voxel row
constexpr int HB   = 4;       // heads per block (window split across 2 blocks)
constexpr int HBC  = HB * C;  // 64 floats of k/v staged per voxel
}

__device__ __forceinline__ float dot4(const float4& a, const float4& b) {
  return a.x * b.x + a.y * b.y + a.z * b.z + a.w * b.w;
}
__device__ __forceinline__ const float4* f4p(const float* p) {
  return reinterpret_cast<const float4*>(p);
}

// Two blocks per window (4 heads each), 256 threads:
//   t -> hl = t>>6 (local head, one per wave), ch = (t>>5)&1 (channel half),
//        i = t&31 (query voxel). h = hb+hl; channels [ch*8, ch*8+8).
// FUSED single j-loop with online softmax (running m/ssum/oacc) — round 9's
// two-pass version spilled lg[32] to scratch (VGPR=64, WRITE_SIZE 232MB) and
// regressed; live state here is ~40 floats so it cannot spill at the 128-VGPR
// cap. One __shfl_xor(,32) per j combines the channel halves.
__global__ __launch_bounds__(256, 4)
void win_attn(const float* __restrict__ qf, const float* __restrict__ kf,
              const float* __restrict__ vf, const float* __restrict__ qt,
              const float* __restrict__ kt, const float* __restrict__ vt,
              const int* __restrict__ toff, const int* __restrict__ widx,
              const int* __restrict__ tidx, float* __restrict__ out)
{
  const int w  = blockIdx.x >> 1;
  const int hb = (blockIdx.x & 1) * HB;   // head base for this block
  const int t  = threadIdx.x;
  const int hl = t >> 6;                  // local head 0..3 (wave id)
  const int ch = (t >> 5) & 1;            // channel half 0..1
  const int i  = t & 31;
  const int h  = hb + hl;                 // global head 0..7
  const int cb = ch * 8;                  // channel base within head

  __shared__ float k_lds[M][HBC];          // 8 KB (4-head slice)
  __shared__ float v_lds[M][HBC];          // 8 KB
  __shared__ int   tid_lds[M * NSIG * M];  // 12 KB, [(j*3+s)*32 + i]
  __shared__ int   vox_lds[M];
  __shared__ int   off_lds[NSIG];

  if (t < M)    vox_lds[t] = widx[w * M + t];
  if (t < NSIG) off_lds[t] = toff[t];
  __syncthreads();

  // Stage the block's 4-head slice of k,v: 512 float4 per table.
  #pragma unroll
  for (int r = 0; r < 2; ++r) {
    const int flat = t + 256 * r;        // [0,512)
    const int j    = flat >> 4;          // voxel 0..31
    const int f4i  = (flat & 15) * 4;    // float index within 64-float slice
    const int goff = vox_lds[j] * HC + hb * C + f4i;
    *reinterpret_cast<float4*>(&k_lds[j][f4i]) = *f4p(kf + goff);
    *reinterpret_cast<float4*>(&v_lds[j][f4i]) = *f4p(vf + goff);
  }
  // Stage table_idx (global layout [i][j][s]) transposed to [(j*3+s)*32+i].
  #pragma unroll
  for (int r = 0; r < 12; ++r) {
    const int g   = t + 256 * r;         // [0,3072)
    const int ii  = g / 96;
    const int rem = g - ii * 96;
    const int jj  = rem / 3;
    const int ss  = rem - jj * 3;
    tid_lds[(jj * NSIG + ss) * M + ii] = tidx[w * (M * M * NSIG) + g];
  }

  // q half-slice for (i,h,ch): 8 floats in registers.
  const int vox_i = vox_lds[i];
  const float* qrow = qf + vox_i * HC + h * C + cb;
  const float4 q0 = f4p(qrow)[0], q1 = f4p(qrow)[1];
  const int offs[NSIG] = { off_lds[0], off_lds[1], off_lds[2] };
  __syncthreads();

  // ---- Fused j-loop: logit -> online softmax -> PV, nothing spillable ----
  float m    = -INFINITY;
  float ssum = 0.f;
  float oacc[8];
  #pragma unroll
  for (int c = 0; c < 8; ++c) oacc[c] = 0.f;

  #pragma unroll
  for (int j = 0; j < M; ++j) {
    const float* krow = &k_lds[j][hl * C + cb];
    const float4 k0 = f4p(krow)[0], k1 = f4p(krow)[1];
    const float4 vv0 = f4p(&v_lds[j][hl * C + cb])[0];
    const float4 vv1 = f4p(&v_lds[j][hl * C + cb])[1];

    float logit = dot4(q0, k0) + dot4(q1, k1);
    float4 tv0[NSIG], tv1[NSIG];
    #pragma unroll
    for (int s = 0; s < NSIG; ++s) {
      const int row = offs[s] + tid_lds[(j * NSIG + s) * M + i];
      const float* base = qt + row * HC + h * C + cb;   // qt row slice
      const float4 a0 = f4p(base)[0], a1 = f4p(base)[1];
      const float* kbase = kt + row * HC + h * C + cb;  // kt row slice
      const float4 b0 = f4p(kbase)[0], b1 = f4p(kbase)[1];
      const float* vbase = vt + row * HC + h * C + cb;  // vt row slice
      tv0[s] = f4p(vbase)[0];
      tv1[s] = f4p(vbase)[1];
      logit += dot4(q0, a0) + dot4(q1, a1) + dot4(k0, b0) + dot4(k1, b1);
    }
    logit += __shfl_xor(logit, 32);   // combine the two channel halves

    const float mnew  = fmaxf(m, logit);
    const float scale = expf(m - mnew);     // ==1 when max unchanged; 0 at j=0
    const float e     = expf(logit - mnew);
    ssum = ssum * scale + e;
    m    = mnew;

    float4 sv0 = tv0[0], sv1 = tv1[0];      // sum of the 3 table-v slices + v
    sv0.x += tv0[1].x + tv0[2].x + vv0.x;  sv0.y += tv0[1].y + tv0[2].y + vv0.y;
    sv0.z += tv0[1].z + tv0[2].z + vv0.z;  sv0.w += tv0[1].w + tv0[2].w + vv0.w;
    sv1.x += tv1[1].x + tv1[2].x + vv1.x;  sv1.y += tv1[1].y + tv1[2].y + vv1.y;
    sv1.z += tv1[1].z + tv1[2].z + vv1.z;  sv1.w += tv1[1].w + tv1[2].w + vv1.w;

    oacc[0] = oacc[0] * scale + e * sv0.x;
    oacc[1] = oacc[1] * scale + e * sv0.y;
    oacc[2] = oacc[2] * scale + e * sv0.z;
    oacc[3] = oacc[3] * scale + e * sv0.w;
    oacc[4] = oacc[4] * scale + e * sv1.x;
    oacc[5] = oacc[5] * scale + e * sv1.y;
    oacc[6] = oacc[6] * scale + e * sv1.z;
    oacc[7] = oacc[7] * scale + e * sv1.w;
  }

  const float inv = 1.0f / ssum;
  float* orow = out + vox_i * HC + h * C + cb;
  float4 o0, o1;
  o0.x = oacc[0] * inv;  o0.y = oacc[1] * inv;
  o0.z = oacc[2] * inv;  o0.w = oacc[3] * inv;
  o1.x = oacc[4] * inv;  o1.y = oacc[5] * inv;
  o1.z = oacc[6] * inv;  o1.w = oacc[7] * inv;
  reinterpret_cast<float4*>(orow)[0] = o0;
  reinterpret_cast<float4*>(orow)[1] = o1;
}

extern "C" void kernel_launch(void* const* d_in, const int* in_sizes, int n_in,
                              void* d_out, int out_size, void* d_ws, size_t ws_size,
                              hipStream_t stream) {
  (void)in_sizes; (void)n_in; (void)d_ws; (void)ws_size; (void)out_size;
  const float* qf  = (const float*)d_in[0];
  const float* kf  = (const float*)d_in[1];
  const float* vf  = (const float*)d_in[2];
  const float* qt  = (const float*)d_in[3];
  const float* kt  = (const float*)d_in[4];
  const float* vt  = (const float*)d_in[5];
  const int*  toff = (const int*)d_in[6];
  const int*  widx = (const int*)d_in[7];
  const int*  tidx = (const int*)d_in[8];
  float* out = (float*)d_out;
  win_attn<<<NWIN * 2, 256, 0, stream>>>(qf, kf, vf, qt, kt, vt, toff, widx, tidx, out);
}